// Round 1
// baseline (663.696 us; speedup 1.0000x reference)
//
#include <hip/hip_runtime.h>
#include <hip/hip_bf16.h>

typedef float  f32x4  __attribute__((ext_vector_type(4)));
typedef __bf16 bf16x8 __attribute__((ext_vector_type(8)));
typedef unsigned int   u32;
typedef unsigned short u16;
typedef u32   u32x2  __attribute__((ext_vector_type(2)));
typedef u16   u16x8  __attribute__((ext_vector_type(8)));
typedef float f32x4g __attribute__((ext_vector_type(4)));

#define DEV __device__ __forceinline__

constexpr int NB = 8, T = 2048, C = 1024, H = 128;
constexpr int BT = NB * T;

union Frag {
  bf16x8 v;
  u32x2  u2[2];
  u32    u[4];
  u16    s[8];
};

DEV u16 f2bu(float f) {
  __hip_bfloat16 h = __float2bfloat16(f);
  return __builtin_bit_cast(u16, h);
}
DEV float bu2f(u16 u) {
  return __bfloat162float(__builtin_bit_cast(__hip_bfloat16, u));
}
DEV f32x4 MFMA(bf16x8 a, bf16x8 b, f32x4 c) {
  return __builtin_amdgcn_mfma_f32_16x16x32_bf16(a, b, c, 0, 0, 0);
}

// ---------------------------------------------------------------------------
// Kernel 0: split W into bf16 hi/lo, stored TRANSPOSED [H][C] so MFMA B-frags
// are contiguous 8B reads. 16384 threads; each owns (h, 8 consecutive c).
// ---------------------------------------------------------------------------
__global__ void prep_w(const float* __restrict__ Wk, const float* __restrict__ Wq,
                       const float* __restrict__ Wv,
                       u16* __restrict__ wtqh, u16* __restrict__ wtql,
                       u16* __restrict__ wtkh, u16* __restrict__ wtkl,
                       u16* __restrict__ wtvh) {
  int id = blockIdx.x * blockDim.x + threadIdx.x;
  if (id >= H * (C / 8)) return;
  int h  = id & (H - 1);
  int c0 = (id >> 7) * 8;
  u16x8 qhv, qlv, khv, klv, vhv;
  #pragma unroll
  for (int j = 0; j < 8; ++j) {
    float q = Wq[(size_t)(c0 + j) * H + h];
    float k = Wk[(size_t)(c0 + j) * H + h];
    float v = Wv[(size_t)(c0 + j) * H + h];
    u16 qh = f2bu(q); qhv[j] = qh; qlv[j] = f2bu(q - bu2f(qh));
    u16 kh = f2bu(k); khv[j] = kh; klv[j] = f2bu(k - bu2f(kh));
    vhv[j] = f2bu(v);
  }
  size_t o = (size_t)h * C + c0;          // 16B aligned (c0 % 8 == 0)
  *(u16x8*)&wtqh[o] = qhv;
  *(u16x8*)&wtql[o] = qlv;
  *(u16x8*)&wtkh[o] = khv;
  *(u16x8*)&wtkl[o] = klv;
  *(u16x8*)&wtvh[o] = vhv;
}

// ---------------------------------------------------------------------------
// Kernel 1: projections q,k,v = x @ {Wq,Wk,Wv}. Split-bf16 3-term MFMA for
// q,k (score precision), single-term for v. M-tile 64 rows, 8 waves
// (waves split the 24 n-tiles by parity). q,k written as hi/lo bf16
// row-major [BT][H]; v written transposed [NB][H][T] for the PV B-operand.
// ---------------------------------------------------------------------------
__global__ __launch_bounds__(512) void proj_kernel(
    const float* __restrict__ x,
    const u16* __restrict__ wtqh, const u16* __restrict__ wtql,
    const u16* __restrict__ wtkh, const u16* __restrict__ wtkl,
    const u16* __restrict__ wtvh,
    u16* __restrict__ qh, u16* __restrict__ ql,
    u16* __restrict__ kh, u16* __restrict__ kl,
    u16* __restrict__ vt) {
  __shared__ u16 xh[64][40];   // stride 40 shorts: 8B-aligned rows, low bank conflict
  __shared__ u16 xl[64][40];
  const int tid  = threadIdx.x;
  const int m0   = blockIdx.x * 64;
  const int wv   = tid >> 6;
  const int lane = tid & 63;
  const int lg   = lane >> 4, lc = lane & 15;
  const int wrow = (wv & 3) * 16;
  const int half = wv >> 2;

  f32x4 zero = {0.f, 0.f, 0.f, 0.f};
  f32x4 acc[12];
  #pragma unroll
  for (int i = 0; i < 12; ++i) acc[i] = zero;

  const int lrow = tid >> 3;          // 0..63
  const int lcol = (tid & 7) * 4;     // 0..28

  for (int kc = 0; kc < C; kc += 32) {
    f32x4g xv = *(const f32x4g*)&x[(size_t)(m0 + lrow) * C + kc + lcol];
    u16 h0s = f2bu(xv[0]); u16 l0s = f2bu(xv[0] - bu2f(h0s));
    u16 h1s = f2bu(xv[1]); u16 l1s = f2bu(xv[1] - bu2f(h1s));
    u16 h2s = f2bu(xv[2]); u16 l2s = f2bu(xv[2] - bu2f(h2s));
    u16 h3s = f2bu(xv[3]); u16 l3s = f2bu(xv[3] - bu2f(h3s));
    u32 hA = h0s | ((u32)h1s << 16), hB = h2s | ((u32)h3s << 16);
    u32 lA = l0s | ((u32)l1s << 16), lB = l2s | ((u32)l3s << 16);
    __syncthreads();                       // previous iter's LDS reads done
    *(u32*)&xh[lrow][lcol]     = hA;
    *(u32*)&xh[lrow][lcol + 2] = hB;
    *(u32*)&xl[lrow][lcol]     = lA;
    *(u32*)&xl[lrow][lcol + 2] = lB;
    __syncthreads();                       // tile ready

    Frag axh, axl;
    axh.u2[0] = *(const u32x2*)&xh[wrow + lc][4 * lg];
    axh.u2[1] = *(const u32x2*)&xh[wrow + lc][16 + 4 * lg];
    axl.u2[0] = *(const u32x2*)&xl[wrow + lc][4 * lg];
    axl.u2[1] = *(const u32x2*)&xl[wrow + lc][16 + 4 * lg];

    #pragma unroll
    for (int i = 0; i < 12; ++i) {
      const int tn  = 2 * i + half;
      const int mat = tn >> 3;             // 0=q 1=k 2=v
      const int h0  = (tn & 7) * 16;
      const u16* bh = (mat == 0) ? wtqh : (mat == 1) ? wtkh : wtvh;
      const size_t boff = (size_t)(h0 + lc) * C + kc + 4 * lg;
      Frag bhf;
      bhf.u2[0] = *(const u32x2*)&bh[boff];
      bhf.u2[1] = *(const u32x2*)&bh[boff + 16];
      acc[i] = MFMA(axh.v, bhf.v, acc[i]);
      if (mat < 2) {
        const u16* bl = (mat == 0) ? wtql : wtkl;
        Frag blf;
        blf.u2[0] = *(const u32x2*)&bl[boff];
        blf.u2[1] = *(const u32x2*)&bl[boff + 16];
        acc[i] = MFMA(axh.v, blf.v, acc[i]);
        acc[i] = MFMA(axl.v, bhf.v, acc[i]);
      }
    }
  }

  // epilogue: D layout col=lane&15, row=4*(lane>>4)+r
  #pragma unroll
  for (int i = 0; i < 12; ++i) {
    const int tn  = 2 * i + half;
    const int mat = tn >> 3;
    const int h0  = (tn & 7) * 16;
    #pragma unroll
    for (int r = 0; r < 4; ++r) {
      const int trow = m0 + wrow + 4 * lg + r;
      const float val = acc[i][r];
      if (mat == 0) {
        u16 hi = f2bu(val);
        qh[(size_t)trow * H + h0 + lc] = hi;
        ql[(size_t)trow * H + h0 + lc] = f2bu(val - bu2f(hi));
      } else if (mat == 1) {
        u16 hi = f2bu(val);
        kh[(size_t)trow * H + h0 + lc] = hi;
        kl[(size_t)trow * H + h0 + lc] = f2bu(val - bu2f(hi));
      } else {
        const int b = trow >> 11, tt = trow & (T - 1);
        vt[((size_t)b * H + h0 + lc) * T + tt] = f2bu(val);
      }
    }
  }
}

// ---------------------------------------------------------------------------
// Kernel 2: causal flash attention. Swapped QK^T (D = K·Q^T) so each lane
// holds the scores of ONE q (=lane&15) and P lands directly in PV's
// A-operand layout. 1 wave per 16 q-rows; K-block 64; online softmax.
// All K/V/Q frag reads straight from global (L2-resident per batch;
// b = blockIdx&7 gives XCD affinity).
// ---------------------------------------------------------------------------
__global__ __launch_bounds__(256) void attn_kernel(
    const u16* __restrict__ qh, const u16* __restrict__ ql,
    const u16* __restrict__ kh, const u16* __restrict__ kl,
    const u16* __restrict__ vt, float* __restrict__ out) {
  const int bid  = blockIdx.x;
  const int b    = bid & 7;
  const int qt   = bid >> 3;            // 0..31 (64-row q-block)
  const int wv   = threadIdx.x >> 6;
  const int lane = threadIdx.x & 63;
  const int lg   = lane >> 4, lc = lane & 15;
  const int q0   = qt * 64 + wv * 16;
  const size_t qbase = (size_t)(b * T + q0);

  // Q as B-operand: lane reads Q[q0+lc][hchunk] contiguous
  Frag bq_h[4], bq_l[4];
  #pragma unroll
  for (int hs = 0; hs < 4; ++hs) {
    const size_t o = (qbase + lc) * H + hs * 32 + 4 * lg;
    bq_h[hs].u2[0] = *(const u32x2*)&qh[o];
    bq_h[hs].u2[1] = *(const u32x2*)&qh[o + 16];
    bq_l[hs].u2[0] = *(const u32x2*)&ql[o];
    bq_l[hs].u2[1] = *(const u32x2*)&ql[o + 16];
  }

  f32x4 zero = {0.f, 0.f, 0.f, 0.f};
  f32x4 o_acc[8];
  #pragma unroll
  for (int i = 0; i < 8; ++i) o_acc[i] = zero;
  float m_run = -INFINITY, l_run = 0.f;

  const int myq = q0 + lc;
  const int nkb = (q0 + 15) >> 6;

  for (int kb = 0; kb <= nkb; ++kb) {
    const size_t kbase = (size_t)(b * T + kb * 64);
    f32x4 s[4];
    #pragma unroll
    for (int t = 0; t < 4; ++t) s[t] = zero;

    #pragma unroll
    for (int hs = 0; hs < 4; ++hs) {
      #pragma unroll
      for (int t = 0; t < 4; ++t) {
        const size_t o = (kbase + t * 16 + lc) * H + hs * 32 + 4 * lg;
        Frag akh, akl;
        akh.u2[0] = *(const u32x2*)&kh[o];
        akh.u2[1] = *(const u32x2*)&kh[o + 16];
        akl.u2[0] = *(const u32x2*)&kl[o];
        akl.u2[1] = *(const u32x2*)&kl[o + 16];
        s[t] = MFMA(akh.v, bq_h[hs].v, s[t]);   // hi*hi
        s[t] = MFMA(akh.v, bq_l[hs].v, s[t]);   // hi*lo
        s[t] = MFMA(akl.v, bq_h[hs].v, s[t]);   // lo*hi
      }
    }

    // scale by sqrt(C)=32, causal mask + (tril==0 -> -inf) semantics
    float pmax = -INFINITY;
    #pragma unroll
    for (int t = 0; t < 4; ++t) {
      #pragma unroll
      for (int r = 0; r < 4; ++r) {
        const int kk = kb * 64 + t * 16 + 4 * lg + r;
        float v = s[t][r] * 32.0f;
        if (kk > myq || v == 0.0f) v = -INFINITY;
        s[t][r] = v;
        pmax = fmaxf(pmax, v);
      }
    }
    pmax = fmaxf(pmax, __shfl_xor(pmax, 16));
    pmax = fmaxf(pmax, __shfl_xor(pmax, 32));
    const float m_new = fmaxf(m_run, pmax);
    const float alpha = __expf(m_run - m_new);

    float sum = 0.f;
    u16 pb[16];
    #pragma unroll
    for (int t = 0; t < 4; ++t) {
      #pragma unroll
      for (int r = 0; r < 4; ++r) {
        float p = __expf(s[t][r] - m_new);
        sum += p;
        pb[t * 4 + r] = f2bu(p);
      }
    }
    sum += __shfl_xor(sum, 16);
    sum += __shfl_xor(sum, 32);
    l_run = l_run * alpha + sum;
    m_run = m_new;

    // rescale O: o-regs' q index is 4*lg+r, alpha lives at lane (4*lg+r)
    float al[4];
    #pragma unroll
    for (int r = 0; r < 4; ++r) al[r] = __shfl(alpha, 4 * lg + r);
    #pragma unroll
    for (int i = 0; i < 8; ++i) {
      #pragma unroll
      for (int r = 0; r < 4; ++r) o_acc[i][r] *= al[r];
    }

    // P already in A-operand layout: A[q=lane&15][kk=4*lg+(i&3)+16*(i>>2)]
    Frag pa[2];
    #pragma unroll
    for (int ks = 0; ks < 2; ++ks) {
      #pragma unroll
      for (int i = 0; i < 8; ++i)
        pa[ks].s[i] = pb[(2 * ks + (i >> 2)) * 4 + (i & 3)];
    }

    #pragma unroll
    for (int ht = 0; ht < 8; ++ht) {
      #pragma unroll
      for (int ks = 0; ks < 2; ++ks) {
        const size_t o = ((size_t)b * H + ht * 16 + lc) * T + kb * 64 + ks * 32 + 4 * lg;
        Frag bvf;
        bvf.u2[0] = *(const u32x2*)&vt[o];
        bvf.u2[1] = *(const u32x2*)&vt[o + 16];
        o_acc[ht] = MFMA(pa[ks].v, bvf.v, o_acc[ht]);
      }
    }
  }

  float li[4];
  #pragma unroll
  for (int r = 0; r < 4; ++r) {
    float lr = __shfl(l_run, 4 * lg + r);
    li[r] = 1.0f / lr;
  }
  #pragma unroll
  for (int ht = 0; ht < 8; ++ht) {
    #pragma unroll
    for (int r = 0; r < 4; ++r)
      out[(qbase + 4 * lg + r) * H + ht * 16 + lc] = o_acc[ht][r] * li[r];
  }
}

// ---------------------------------------------------------------------------
extern "C" void kernel_launch(void* const* d_in, const int* in_sizes, int n_in,
                              void* d_out, int out_size, void* d_ws, size_t ws_size,
                              hipStream_t stream) {
  (void)in_sizes; (void)n_in; (void)out_size; (void)ws_size;
  const float* x  = (const float*)d_in[0];
  const float* Wk = (const float*)d_in[1];   // setup_inputs order: x, Wk, Wq, Wv
  const float* Wq = (const float*)d_in[2];
  const float* Wv = (const float*)d_in[3];
  float* out = (float*)d_out;

  u16* w = (u16*)d_ws;
  const size_t WSZ = (size_t)C * H;    // 131072
  const size_t PSZ = (size_t)BT * H;   // 2097152
  u16* wtqh = w;
  u16* wtql = wtqh + WSZ;
  u16* wtkh = wtql + WSZ;
  u16* wtkl = wtkh + WSZ;
  u16* wtvh = wtkl + WSZ;
  u16* qhp  = wtvh + WSZ;
  u16* qlp  = qhp + PSZ;
  u16* khp  = qlp + PSZ;
  u16* klp  = khp + PSZ;
  u16* vtp  = klp + PSZ;               // total ~22.3 MB of ws

  prep_w<<<64, 256, 0, stream>>>(Wk, Wq, Wv, wtqh, wtql, wtkh, wtkl, wtvh);
  proj_kernel<<<BT / 64, 512, 0, stream>>>(x, wtqh, wtql, wtkh, wtkl, wtvh,
                                           qhp, qlp, khp, klp, vtp);
  attn_kernel<<<NB * (T / 64), 256, 0, stream>>>(qhp, qlp, khp, klp, vtp, out);
}

// Round 2
// 262.900 us; speedup vs baseline: 2.5245x; 2.5245x over previous
//
#include <hip/hip_runtime.h>
#include <hip/hip_bf16.h>

typedef float  f32x4  __attribute__((ext_vector_type(4)));
typedef __bf16 bf16x8 __attribute__((ext_vector_type(8)));
typedef unsigned int   u32;
typedef unsigned short u16;
typedef u32   u32x2  __attribute__((ext_vector_type(2)));
typedef u32   u32x4  __attribute__((ext_vector_type(4)));
typedef u16   u16x8  __attribute__((ext_vector_type(8)));

#define DEV __device__ __forceinline__

constexpr int NB = 8, T = 2048, C = 1024, H = 128;
constexpr int BT = NB * T;

union Frag {
  bf16x8 v;
  u32x4  u4;
  u32x2  u2[2];
  u32    u[4];
  u16    s[8];
};

DEV u16 f2bu(float f) {
  __hip_bfloat16 h = __float2bfloat16(f);
  return __builtin_bit_cast(u16, h);
}
DEV float bu2f(u16 u) {
  return __bfloat162float(__builtin_bit_cast(__hip_bfloat16, u));
}
DEV f32x4 MFMA(bf16x8 a, bf16x8 b, f32x4 c) {
  return __builtin_amdgcn_mfma_f32_16x16x32_bf16(a, b, c, 0, 0, 0);
}

// ---------------------------------------------------------------------------
// Fragment-packed layouts (consumer = 16x16x32 MFMA, A[m=lane&15][k=4*(lane>>4)
// +(e&3)+16*(e>>2)], B[n=lane&15][k=same], D[col=lane&15][row=4*(lane>>4)+r]):
//   wpq/wpk: [tile8][kc32][lane64][hl2][e8]  (32B/lane: hi 16B + lo 16B)
//   wpv:     [tile8][kc32][lane64][e8]       (16B/lane)
//   qpk/kpk: [b][t16-tile 128][lane64][hs4][hl2][e8]  (per hs: 32B hi+lo)
//   vpk:     [b][k32-tile 64][lane64][ht8][e8]
// ---------------------------------------------------------------------------

// Kernel 0: pack W into per-fragment layout, bf16 hi/lo split for Wq/Wk.
__global__ void prep_w(const float* __restrict__ Wk, const float* __restrict__ Wq,
                       const float* __restrict__ Wv,
                       u16* __restrict__ wpq, u16* __restrict__ wpk,
                       u16* __restrict__ wpv) {
  const int id = blockIdx.x * 256 + threadIdx.x;   // 24*32*64 = 49152
  if (id >= 24 * 32 * 64) return;
  const int lane = id & 63;
  const int kc   = (id >> 6) & 31;
  const int tile = id >> 11;          // 0..23
  const int mat  = tile >> 3;         // 0=q 1=k 2=v
  const int tt   = tile & 7;
  const int n    = tt * 16 + (lane & 15);
  const float* W = (mat == 0) ? Wq : (mat == 1) ? Wk : Wv;
  u16x8 hi, lo;
  #pragma unroll
  for (int e = 0; e < 8; ++e) {
    const int k = kc * 32 + 4 * (lane >> 4) + (e & 3) + 16 * (e >> 2);
    const float w = W[(size_t)k * H + n];
    u16 h = f2bu(w);
    hi[e] = h;
    lo[e] = f2bu(w - bu2f(h));
  }
  if (mat == 2) {
    *(u16x8*)(wpv + ((size_t)(tt * 32 + kc) * 64 + lane) * 8) = hi;
  } else {
    u16* p = ((mat == 0) ? wpq : wpk) + ((size_t)(tt * 32 + kc) * 64 + lane) * 16;
    *(u16x8*)p       = hi;
    *(u16x8*)(p + 8) = lo;
  }
}

// ---------------------------------------------------------------------------
// Kernel 1: projections. One wave per (16-row tile, half). No LDS, no
// barriers: pure streaming MFMA, compiler-pipelined. 2048 waves.
// ---------------------------------------------------------------------------
__global__ __launch_bounds__(256, 4) void proj_kernel(
    const float* __restrict__ x,
    const u16* __restrict__ wpq, const u16* __restrict__ wpk,
    const u16* __restrict__ wpv,
    u16* __restrict__ qpk, u16* __restrict__ kpk, u16* __restrict__ vpk) {
  const int wid  = (blockIdx.x * 256 + threadIdx.x) >> 6;  // 0..2047
  const int lane = threadIdx.x & 63;
  const int rt   = wid >> 1;       // 16-row tile 0..1023
  const int half = wid & 1;        // n-tile parity
  const int lg   = lane >> 4, lc = lane & 15;
  const int row  = rt * 16 + lc;

  f32x4 zero = {0.f, 0.f, 0.f, 0.f};
  f32x4 acc[12];
  #pragma unroll
  for (int i = 0; i < 12; ++i) acc[i] = zero;

  for (int kc = 0; kc < 32; ++kc) {
    const f32x4 xa = *(const f32x4*)&x[(size_t)row * C + kc * 32 + 4 * lg];
    const f32x4 xb = *(const f32x4*)&x[(size_t)row * C + kc * 32 + 16 + 4 * lg];
    Frag axh, axl;
    #pragma unroll
    for (int e = 0; e < 4; ++e) {
      u16 h = f2bu(xa[e]);
      axh.s[e] = h; axl.s[e] = f2bu(xa[e] - bu2f(h));
      u16 h2 = f2bu(xb[e]);
      axh.s[e + 4] = h2; axl.s[e + 4] = f2bu(xb[e] - bu2f(h2));
    }
    #pragma unroll
    for (int i = 0; i < 12; ++i) {
      const int tn = 2 * i + half;
      const int mat = tn >> 3, tt = tn & 7;
      if (mat < 2) {
        const u16* p = ((mat == 0) ? wpq : wpk) +
                       ((size_t)(tt * 32 + kc) * 64 + lane) * 16;
        Frag bh, bl;
        bh.u4 = *(const u32x4*)p;
        bl.u4 = *(const u32x4*)(p + 8);
        acc[i] = MFMA(axh.v, bh.v, acc[i]);
        acc[i] = MFMA(axh.v, bl.v, acc[i]);
        acc[i] = MFMA(axl.v, bh.v, acc[i]);
      } else {
        Frag bh;
        bh.u4 = *(const u32x4*)(wpv + ((size_t)(tt * 32 + kc) * 64 + lane) * 8);
        acc[i] = MFMA(axh.v, bh.v, acc[i]);
      }
    }
  }

  // Epilogue: D[col=lc -> h within tile][row=4lg+r -> time within 16].
  const int b  = rt >> 7;
  const int tb = rt & 127;
  #pragma unroll
  for (int i = 0; i < 12; ++i) {
    const int tn = 2 * i + half;
    const int mat = tn >> 3, tt = tn & 7;
    #pragma unroll
    for (int r = 0; r < 4; ++r) {
      const float val = acc[i][r];
      if (mat < 2) {
        // q/k packed: lane_c = (4lg+r) + 16*(lc>>2); hs = tt>>1; e = (lc&3)+4*(tt&1)
        const u16 hv = f2bu(val);
        const u16 lv = f2bu(val - bu2f(hv));
        const int lane_c = 4 * lg + r + 16 * (lc >> 2);
        const int hs = tt >> 1;
        const int e  = (lc & 3) + 4 * (tt & 1);
        u16* dst = ((mat == 0) ? qpk : kpk) +
                   ((((size_t)(b * 128 + tb) * 64 + lane_c) * 4 + hs) * 2) * 8 + e;
        dst[0] = hv;   // hl=0
        dst[8] = lv;   // hl=1
      } else {
        // v packed: tb32 = tb>>1; lane_c = lc + 16*lg; ht = tt; e = r + 4*(tb&1)
        const u16 hv = f2bu(val);
        const int tb32 = tb >> 1;
        const int lane_c = lc + 16 * lg;
        const int e = r + 4 * (tb & 1);
        vpk[(((size_t)(b * 64 + tb32) * 64 + lane_c) * 8 + tt) * 8 + e] = hv;
      }
    }
  }
}

// ---------------------------------------------------------------------------
// Kernel 2: causal flash attention with intra-block split-K.
// Block = one 16-row q-tile, 8 waves; wave w takes kb = w, w+8, ...
// Swapped QK^T (D=K·Q^T) so P lands in PV's A-operand layout. Partials
// merged through LDS.
// ---------------------------------------------------------------------------
__global__ __launch_bounds__(512, 4) void attn_kernel(
    const u16* __restrict__ qpk, const u16* __restrict__ kpk,
    const u16* __restrict__ vpk, float* __restrict__ out) {
  __shared__ float lm[8][16];
  __shared__ float ll[8][16];
  __shared__ float lo[8][16][132];   // +4 pad: lg groups hit distinct banks

  const int bid = blockIdx.x;
  const int b   = bid & 7;           // batch -> XCD affinity
  const int qt  = bid >> 3;          // 0..127
  const int w    = threadIdx.x >> 6;
  const int lane = threadIdx.x & 63;
  const int lg = lane >> 4, lc = lane & 15;

  // Q fragments (packed, 32B per hs: hi+lo)
  Frag bqh[4], bql[4];
  const u16* qp = qpk + ((size_t)(b * 128 + qt) * 64 + lane) * 64;
  #pragma unroll
  for (int hs = 0; hs < 4; ++hs) {
    bqh[hs].u4 = *(const u32x4*)(qp + hs * 16);
    bql[hs].u4 = *(const u32x4*)(qp + hs * 16 + 8);
  }

  f32x4 zero = {0.f, 0.f, 0.f, 0.f};
  f32x4 o_acc[8];
  #pragma unroll
  for (int i = 0; i < 8; ++i) o_acc[i] = zero;
  float m_run = -INFINITY, l_run = 0.f;

  const int myq = qt * 16 + lc;
  const int nkb = qt >> 2;           // last 64-wide k-block

  for (int kb = w; kb <= nkb; kb += 8) {
    f32x4 s[4];
    #pragma unroll
    for (int t = 0; t < 4; ++t) s[t] = zero;

    const u16* kp = kpk + ((size_t)(b * 128 + kb * 4) * 64 + lane) * 64;
    #pragma unroll
    for (int t = 0; t < 4; ++t) {
      #pragma unroll
      for (int hs = 0; hs < 4; ++hs) {
        const u16* p = kp + t * 4096 + hs * 16;
        Frag akh, akl;
        akh.u4 = *(const u32x4*)p;
        akl.u4 = *(const u32x4*)(p + 8);
        s[t] = MFMA(akh.v, bqh[hs].v, s[t]);
        s[t] = MFMA(akh.v, bql[hs].v, s[t]);
        s[t] = MFMA(akl.v, bqh[hs].v, s[t]);
      }
    }

    // scale by sqrt(C)=32; causal + (tril==0 -> -inf) semantics
    float pmax = -INFINITY;
    #pragma unroll
    for (int t = 0; t < 4; ++t) {
      #pragma unroll
      for (int r = 0; r < 4; ++r) {
        const int kk = kb * 64 + t * 16 + 4 * lg + r;
        float v = s[t][r] * 32.0f;
        if (kk > myq || v == 0.0f) v = -INFINITY;
        s[t][r] = v;
        pmax = fmaxf(pmax, v);
      }
    }
    pmax = fmaxf(pmax, __shfl_xor(pmax, 16));
    pmax = fmaxf(pmax, __shfl_xor(pmax, 32));
    const float m_new = fmaxf(m_run, pmax);
    const float alpha = __expf(m_run - m_new);

    float sum = 0.f;
    u16 pb[16];
    #pragma unroll
    for (int t = 0; t < 4; ++t) {
      #pragma unroll
      for (int r = 0; r < 4; ++r) {
        const float p = __expf(s[t][r] - m_new);
        sum += p;
        pb[t * 4 + r] = f2bu(p);
      }
    }
    sum += __shfl_xor(sum, 16);
    sum += __shfl_xor(sum, 32);
    l_run = l_run * alpha + sum;
    m_run = m_new;

    float al[4];
    #pragma unroll
    for (int r = 0; r < 4; ++r) al[r] = __shfl(alpha, 4 * lg + r);
    #pragma unroll
    for (int i = 0; i < 8; ++i) {
      #pragma unroll
      for (int r = 0; r < 4; ++r) o_acc[i][r] *= al[r];
    }

    Frag pa[2];
    #pragma unroll
    for (int ks = 0; ks < 2; ++ks) {
      #pragma unroll
      for (int e = 0; e < 8; ++e)
        pa[ks].s[e] = pb[(2 * ks + (e >> 2)) * 4 + (e & 3)];
    }

    #pragma unroll
    for (int ks = 0; ks < 2; ++ks) {
      const u16* vp = vpk + ((size_t)(b * 64 + kb * 2 + ks) * 64 + lane) * 64;
      #pragma unroll
      for (int ht = 0; ht < 8; ++ht) {
        Frag bv;
        bv.u4 = *(const u32x4*)(vp + ht * 8);
        o_acc[ht] = MFMA(pa[ks].v, bv.v, o_acc[ht]);
      }
    }
  }

  // --- combine 8 partials through LDS ---
  if (lane < 16) { lm[w][lane] = m_run; ll[w][lane] = l_run; }
  #pragma unroll
  for (int ht = 0; ht < 8; ++ht)
    #pragma unroll
    for (int r = 0; r < 4; ++r)
      lo[w][4 * lg + r][ht * 16 + lc] = o_acc[ht][r];
  __syncthreads();

  const int tid = threadIdx.x;
  const int q  = tid >> 5;            // 0..15
  const int hb = (tid & 31) * 4;      // 0..124
  float M = -INFINITY;
  #pragma unroll
  for (int ww = 0; ww < 8; ++ww) M = fmaxf(M, lm[ww][q]);
  float lsum = 0.f;
  f32x4 osum = {0.f, 0.f, 0.f, 0.f};
  #pragma unroll
  for (int ww = 0; ww < 8; ++ww) {
    const float sc = __expf(lm[ww][q] - M);
    lsum += sc * ll[ww][q];
    const f32x4 ov = *(const f32x4*)&lo[ww][q][hb];
    #pragma unroll
    for (int j = 0; j < 4; ++j) osum[j] += sc * ov[j];
  }
  const float inv = 1.0f / lsum;
  f32x4 res = {osum[0] * inv, osum[1] * inv, osum[2] * inv, osum[3] * inv};
  *(f32x4*)&out[((size_t)(b * T + qt * 16 + q)) * H + hb] = res;
}

// ---------------------------------------------------------------------------
extern "C" void kernel_launch(void* const* d_in, const int* in_sizes, int n_in,
                              void* d_out, int out_size, void* d_ws, size_t ws_size,
                              hipStream_t stream) {
  (void)in_sizes; (void)n_in; (void)out_size; (void)ws_size;
  const float* x  = (const float*)d_in[0];
  const float* Wk = (const float*)d_in[1];
  const float* Wq = (const float*)d_in[2];
  const float* Wv = (const float*)d_in[3];
  float* out = (float*)d_out;

  u16* w = (u16*)d_ws;
  const size_t WPQK = (size_t)8 * 32 * 64 * 16;   // 262144
  const size_t WPV  = (size_t)8 * 32 * 64 * 8;    // 131072
  const size_t QKP  = (size_t)NB * 128 * 64 * 64; // 4194304
  const size_t VP   = (size_t)NB * 64 * 64 * 64;  // 2097152
  u16* wpq = w;
  u16* wpk = wpq + WPQK;
  u16* wpv = wpk + WPQK;
  u16* qpk = wpv + WPV;
  u16* kpk = qpk + QKP;
  u16* vpk = kpk + QKP;               // total ~22.3 MB

  prep_w<<<192, 256, 0, stream>>>(Wk, Wq, Wv, wpq, wpk, wpv);
  proj_kernel<<<512, 256, 0, stream>>>(x, wpq, wpk, wpv, qpk, kpk, vpk);
  attn_kernel<<<NB * (T / 16), 512, 0, stream>>>(qpk, kpk, vpk, out);
}

// Round 4
// 118.760 us; speedup vs baseline: 5.5886x; 2.2137x over previous
//
#include <hip/hip_runtime.h>
#include <hip/hip_bf16.h>

typedef float  f32x4  __attribute__((ext_vector_type(4)));
typedef __bf16 bf16x8 __attribute__((ext_vector_type(8)));
typedef unsigned int   u32;
typedef unsigned short u16;
typedef u32   u32x2  __attribute__((ext_vector_type(2)));
typedef u32   u32x4  __attribute__((ext_vector_type(4)));
typedef u16   u16x4  __attribute__((ext_vector_type(4)));
typedef u16   u16x8  __attribute__((ext_vector_type(8)));

#define DEV __device__ __forceinline__

constexpr int NB = 8, T = 2048, C = 1024, H = 128;
constexpr int BT = NB * T;

union Frag {
  bf16x8 v;
  u32x4  u4;
  u32x2  u2[2];
  u32    u[4];
  u16    s[8];
};

DEV u16 f2bu(float f) {
  __hip_bfloat16 h = __float2bfloat16(f);
  return __builtin_bit_cast(u16, h);
}
DEV float bu2f(u16 u) {
  return __bfloat162float(__builtin_bit_cast(__hip_bfloat16, u));
}
DEV f32x4 MFMA(bf16x8 a, bf16x8 b, f32x4 c) {
  return __builtin_amdgcn_mfma_f32_16x16x32_bf16(a, b, c, 0, 0, 0);
}

// ---------------------------------------------------------------------------
// Lane-contiguous fragment layouts: every 16B fragment load instruction reads
// a contiguous 1KB block across the wave's 64 lanes.
//   wpq/wpk: [tt8][kc32][hl2][lane64][e8]        (tile stride in u16: 1024)
//   wpv:     [tt8][kc32][lane64][e8]             (512)
//   qpk/kpk: [b8][tile128][hs4][hl2][lane64][e8] (tile stride 4096)
//   vpk:     [b8][kt64][ht8][lane64][e8]         (kt stride 4096)
// Frag element mapping (16x16x32): lane = n + 16*((k32>>2)&3),
//                                  e = (k32&3) + 4*(k32>>4).
// ---------------------------------------------------------------------------

// Kernel 0: pack W, bf16 hi/lo split for Wq/Wk.
__global__ void prep_w(const float* __restrict__ Wk, const float* __restrict__ Wq,
                       const float* __restrict__ Wv,
                       u16* __restrict__ wpq, u16* __restrict__ wpk,
                       u16* __restrict__ wpv) {
  const int id = blockIdx.x * 256 + threadIdx.x;   // 24*32*64 = 49152
  if (id >= 24 * 32 * 64) return;
  const int lane = id & 63;
  const int kc   = (id >> 6) & 31;
  const int tile = id >> 11;          // 0..23
  const int mat  = tile >> 3;         // 0=q 1=k 2=v
  const int tt   = tile & 7;
  const int n    = tt * 16 + (lane & 15);
  const float* W = (mat == 0) ? Wq : (mat == 1) ? Wk : Wv;
  u16x8 hi, lo;
  #pragma unroll
  for (int e = 0; e < 8; ++e) {
    const int k = kc * 32 + 4 * (lane >> 4) + (e & 3) + 16 * (e >> 2);
    const float w = W[(size_t)k * H + n];
    u16 h = f2bu(w);
    hi[e] = h;
    lo[e] = f2bu(w - bu2f(h));
  }
  if (mat == 2) {
    *(u16x8*)(wpv + ((size_t)(tt * 32 + kc) * 64 + lane) * 8) = hi;
  } else {
    u16* p = ((mat == 0) ? wpq : wpk) +
             (((size_t)(tt * 32 + kc) * 2 + 0) * 64 + lane) * 8;
    *(u16x8*)p         = hi;
    *(u16x8*)(p + 512) = lo;          // hl stride = 64*8
  }
}

// ---------------------------------------------------------------------------
// Kernel 1: projections, LDS-staged x (coalesced global reads), 1024 threads
// = 16 waves: wave = (msub = w&3 -> 16 rows, nq = w>>2 -> 6 n-tiles).
// Split-bf16 3-term MFMA for q,k; single for v.
// ---------------------------------------------------------------------------
__global__ __launch_bounds__(1024, 4) void proj_kernel(
    const float* __restrict__ x,
    const u16* __restrict__ wpq, const u16* __restrict__ wpk,
    const u16* __restrict__ wpv,
    u16* __restrict__ qpk, u16* __restrict__ kpk, u16* __restrict__ vpk) {
  __shared__ u16 xh[64][72];   // stride 72 u16 = 144B: 8B-aligned, 2-way-free banks
  __shared__ u16 xl[64][72];
  const int tid  = threadIdx.x;
  const int m0   = blockIdx.x * 64;
  const int w    = tid >> 6;
  const int lane = tid & 63;
  const int lg   = lane >> 4, lc = lane & 15;
  const int wrow = (w & 3) * 16;
  const int nq   = w >> 2;                 // 0..3

  f32x4 zero = {0.f, 0.f, 0.f, 0.f};
  f32x4 acc[6];
  #pragma unroll
  for (int i = 0; i < 6; ++i) acc[i] = zero;

  const int lrow = tid >> 4;          // 0..63
  const int lcol = (tid & 15) * 4;    // 0..60

  for (int ks = 0; ks < 16; ++ks) {
    const f32x4 xv = *(const f32x4*)&x[(size_t)(m0 + lrow) * C + ks * 64 + lcol];
    u16x4 hv, lv;
    #pragma unroll
    for (int e = 0; e < 4; ++e) {
      u16 h = f2bu(xv[e]);
      hv[e] = h;
      lv[e] = f2bu(xv[e] - bu2f(h));
    }
    __syncthreads();                       // previous step's LDS reads done
    *(u16x4*)&xh[lrow][lcol] = hv;
    *(u16x4*)&xl[lrow][lcol] = lv;
    __syncthreads();                       // tile ready

    #pragma unroll
    for (int kc = 0; kc < 2; ++kc) {
      Frag axh, axl;
      axh.u2[0] = *(const u32x2*)&xh[wrow + lc][kc * 32 + 4 * lg];
      axh.u2[1] = *(const u32x2*)&xh[wrow + lc][kc * 32 + 16 + 4 * lg];
      axl.u2[0] = *(const u32x2*)&xl[wrow + lc][kc * 32 + 4 * lg];
      axl.u2[1] = *(const u32x2*)&xl[wrow + lc][kc * 32 + 16 + 4 * lg];
      const int kcg = ks * 2 + kc;         // global 32-col chunk 0..31

      #pragma unroll
      for (int i = 0; i < 6; ++i) {
        const int tn = nq + 4 * i;         // 0..23
        const int mat = tn >> 3, tt = tn & 7;
        if (mat < 2) {
          const u16* pw = ((mat == 0) ? wpq : wpk) +
                          ((size_t)(tt * 32 + kcg) * 2 * 64 + lane) * 8;
          Frag bh, bl;
          bh.u4 = *(const u32x4*)pw;
          bl.u4 = *(const u32x4*)(pw + 512);
          acc[i] = MFMA(axh.v, bh.v, acc[i]);
          acc[i] = MFMA(axh.v, bl.v, acc[i]);
          acc[i] = MFMA(axl.v, bh.v, acc[i]);
        } else {
          Frag bh;
          bh.u4 = *(const u32x4*)(wpv + ((size_t)(tt * 32 + kcg) * 64 + lane) * 8);
          acc[i] = MFMA(axh.v, bh.v, acc[i]);
        }
      }
    }
  }

  // Epilogue. Value = Out[m0+wrow+4lg+r][tn*16+lc].
  const int tb_abs = (m0 + wrow) >> 4;
  const int b  = tb_abs >> 7;
  const int tb = tb_abs & 127;
  #pragma unroll
  for (int i = 0; i < 6; ++i) {
    const int tn = nq + 4 * i;
    const int mat = tn >> 3, tt = tn & 7;
    #pragma unroll
    for (int r = 0; r < 4; ++r) {
      const float val = acc[i][r];
      if (mat < 2) {
        const u16 hvv = f2bu(val);
        const u16 lvv = f2bu(val - bu2f(hvv));
        const int lane_c = 4 * lg + r + 16 * (lc >> 2);
        const int hs = tt >> 1;
        const int e  = (lc & 3) + 4 * (tt & 1);
        u16* dst = ((mat == 0) ? qpk : kpk) +
                   (((size_t)(b * 128 + tb) * 4 + hs) * 2 * 64 + lane_c) * 8 + e;
        dst[0]   = hvv;   // hl=0
        dst[512] = lvv;   // hl=1
      } else {
        const int kt = tb >> 1;
        const int lane_c = lc + 16 * lg;
        const int e = r + 4 * (tb & 1);
        vpk[(((size_t)(b * 64 + kt) * 8 + tt) * 64 + lane_c) * 8 + e] = f2bu(val);
      }
    }
  }
}

// ---------------------------------------------------------------------------
// Kernel 2: causal flash attention, intra-block split-K (8 waves, wave w
// takes kb = w, w+8, ...). Swapped QK^T so P lands in PV's A-operand layout.
// Partials merged via LDS (partial O as bf16 to fit 4 blocks/CU).
// ---------------------------------------------------------------------------
__global__ __launch_bounds__(512, 4) void attn_kernel(
    const u16* __restrict__ qpk, const u16* __restrict__ kpk,
    const u16* __restrict__ vpk, float* __restrict__ out) {
  __shared__ float lm[8][16];
  __shared__ float ll[8][16];
  __shared__ u16 lo[8][16][132];     // bf16 partial O, stride 132: 8B-aligned rows

  const int bid = blockIdx.x;
  const int b   = bid & 7;           // batch -> XCD affinity
  const int qt  = bid >> 3;          // 0..127
  const int w    = threadIdx.x >> 6;
  const int lane = threadIdx.x & 63;
  const int lg = lane >> 4, lc = lane & 15;

  // Q fragments: [b][qt][hs][hl][lane][8], tile stride 4096 u16
  Frag bqh[4], bql[4];
  const u16* qp = qpk + (size_t)(b * 128 + qt) * 4096 + lane * 8;
  #pragma unroll
  for (int hs = 0; hs < 4; ++hs) {
    bqh[hs].u4 = *(const u32x4*)(qp + (size_t)(hs * 2 + 0) * 512);
    bql[hs].u4 = *(const u32x4*)(qp + (size_t)(hs * 2 + 1) * 512);
  }

  f32x4 zero = {0.f, 0.f, 0.f, 0.f};
  f32x4 o_acc[8];
  #pragma unroll
  for (int i = 0; i < 8; ++i) o_acc[i] = zero;
  float m_run = -INFINITY, l_run = 0.f;

  const int myq = qt * 16 + lc;
  const int nkb = qt >> 2;           // last 64-wide k-block

  for (int kb = w; kb <= nkb; kb += 8) {
    f32x4 s[4];
    #pragma unroll
    for (int t = 0; t < 4; ++t) s[t] = zero;

    const u16* kp = kpk + (size_t)(b * 128 + kb * 4) * 4096 + lane * 8;
    #pragma unroll
    for (int t = 0; t < 4; ++t) {
      #pragma unroll
      for (int hs = 0; hs < 4; ++hs) {
        const u16* p = kp + (size_t)(t * 8 + hs * 2) * 512;
        Frag akh, akl;
        akh.u4 = *(const u32x4*)p;
        akl.u4 = *(const u32x4*)(p + 512);
        s[t] = MFMA(akh.v, bqh[hs].v, s[t]);
        s[t] = MFMA(akh.v, bql[hs].v, s[t]);
        s[t] = MFMA(akl.v, bqh[hs].v, s[t]);
      }
    }

    // scale by sqrt(C)=32; causal + (tril==0 -> -inf) semantics
    float pmax = -INFINITY;
    #pragma unroll
    for (int t = 0; t < 4; ++t) {
      #pragma unroll
      for (int r = 0; r < 4; ++r) {
        const int kk = kb * 64 + t * 16 + 4 * lg + r;
        float v = s[t][r] * 32.0f;
        if (kk > myq || v == 0.0f) v = -INFINITY;
        s[t][r] = v;
        pmax = fmaxf(pmax, v);
      }
    }
    pmax = fmaxf(pmax, __shfl_xor(pmax, 16));
    pmax = fmaxf(pmax, __shfl_xor(pmax, 32));
    const float m_new = fmaxf(m_run, pmax);
    const float alpha = __expf(m_run - m_new);

    float sum = 0.f;
    u16 pb[16];
    #pragma unroll
    for (int t = 0; t < 4; ++t) {
      #pragma unroll
      for (int r = 0; r < 4; ++r) {
        const float p = __expf(s[t][r] - m_new);
        sum += p;
        pb[t * 4 + r] = f2bu(p);
      }
    }
    sum += __shfl_xor(sum, 16);
    sum += __shfl_xor(sum, 32);
    l_run = l_run * alpha + sum;
    m_run = m_new;

    float al[4];
    #pragma unroll
    for (int r = 0; r < 4; ++r) al[r] = __shfl(alpha, 4 * lg + r);
    #pragma unroll
    for (int i = 0; i < 8; ++i) {
      #pragma unroll
      for (int r = 0; r < 4; ++r) o_acc[i][r] *= al[r];
    }

    Frag pa[2];
    #pragma unroll
    for (int ks = 0; ks < 2; ++ks) {
      #pragma unroll
      for (int e = 0; e < 8; ++e)
        pa[ks].s[e] = pb[(2 * ks + (e >> 2)) * 4 + (e & 3)];
    }

    #pragma unroll
    for (int ks = 0; ks < 2; ++ks) {
      const u16* vp = vpk + (size_t)(b * 64 + kb * 2 + ks) * 4096 + lane * 8;
      #pragma unroll
      for (int ht = 0; ht < 8; ++ht) {
        Frag bv;
        bv.u4 = *(const u32x4*)(vp + (size_t)ht * 512);
        o_acc[ht] = MFMA(pa[ks].v, bv.v, o_acc[ht]);
      }
    }
  }

  // --- combine 8 partials through LDS ---
  if (lane < 16) { lm[w][lane] = m_run; ll[w][lane] = l_run; }
  #pragma unroll
  for (int ht = 0; ht < 8; ++ht)
    #pragma unroll
    for (int r = 0; r < 4; ++r)
      lo[w][4 * lg + r][ht * 16 + lc] = f2bu(o_acc[ht][r]);
  __syncthreads();

  const int tid = threadIdx.x;
  const int q  = tid >> 5;            // 0..15
  const int hb = (tid & 31) * 4;      // 0..124
  float M = -INFINITY;
  #pragma unroll
  for (int ww = 0; ww < 8; ++ww) M = fmaxf(M, lm[ww][q]);
  float lsum = 0.f;
  f32x4 osum = {0.f, 0.f, 0.f, 0.f};
  #pragma unroll
  for (int ww = 0; ww < 8; ++ww) {
    const float sc = __expf(lm[ww][q] - M);
    lsum += sc * ll[ww][q];
    const u16x4 ov = *(const u16x4*)&lo[ww][q][hb];
    #pragma unroll
    for (int j = 0; j < 4; ++j) osum[j] += sc * bu2f(ov[j]);
  }
  const float inv = 1.0f / lsum;
  f32x4 res = {osum[0] * inv, osum[1] * inv, osum[2] * inv, osum[3] * inv};
  *(f32x4*)&out[((size_t)(b * T + qt * 16 + q)) * H + hb] = res;
}

// ---------------------------------------------------------------------------
extern "C" void kernel_launch(void* const* d_in, const int* in_sizes, int n_in,
                              void* d_out, int out_size, void* d_ws, size_t ws_size,
                              hipStream_t stream) {
  (void)in_sizes; (void)n_in; (void)out_size; (void)ws_size;
  const float* x  = (const float*)d_in[0];
  const float* Wk = (const float*)d_in[1];
  const float* Wq = (const float*)d_in[2];
  const float* Wv = (const float*)d_in[3];
  float* out = (float*)d_out;

  u16* w = (u16*)d_ws;
  const size_t WPQK = (size_t)8 * 32 * 2 * 64 * 8;   // 262144
  const size_t WPV  = (size_t)8 * 32 * 64 * 8;       // 131072
  const size_t QKP  = (size_t)NB * 128 * 4 * 2 * 64 * 8; // 4194304
  const size_t VP   = (size_t)NB * 64 * 8 * 64 * 8;  // 2097152
  u16* wpq = w;
  u16* wpk = wpq + WPQK;
  u16* wpv = wpk + WPQK;
  u16* qpk = wpv + WPV;
  u16* kpk = qpk + QKP;
  u16* vpk = kpk + QKP;               // total ~22.3 MB

  prep_w<<<192, 256, 0, stream>>>(Wk, Wq, Wv, wpq, wpk, wpv);
  proj_kernel<<<BT / 64, 1024, 0, stream>>>(x, wpq, wpk, wpv, qpk, kpk, vpk);
  attn_kernel<<<NB * (T / 16), 512, 0, stream>>>(qpk, kpk, vpk, out);
}